// Round 3
// baseline (312.788 us; speedup 1.0000x reference)
//
#include <hip/hip_runtime.h>
#include <hip/hip_bf16.h>
#include <math.h>

typedef __bf16 bf16_t;
typedef bf16_t bf16x8 __attribute__((ext_vector_type(8)));
typedef float f32x4 __attribute__((ext_vector_type(4)));
typedef unsigned int u32;

#define B_SZ 4096
#define P_HID 1024
#define H_HID 512
#define MAX_P 128
#define MAX_HE 42
#define HE_PAD 64
#define E_MAX 8128
#define E_MAX4 2032

// ---------------------------------------------------------------------------
__device__ __forceinline__ void async_cp16(const bf16_t* g, bf16_t* l) {
    __builtin_amdgcn_global_load_lds(
        (const __attribute__((address_space(1))) u32*)g,
        (__attribute__((address_space(3))) u32*)l, 16, 0, 0);
}

__device__ __forceinline__ float gelu_exact(float v) {
    return 0.5f * v * (1.f + erff(v * 0.70710678118654752f));
}

// ---------------------------------------------------------------------------
// GEMM1: C = gelu(A@B + bias), split-bf16 3-MFMA, output as split planes.
// A planes [M][K], BT planes [N][K]. BM x BN tile, BK=32, 4 waves (2x2).
// ---------------------------------------------------------------------------
template<int BM, int BN>
__global__ __launch_bounds__(256, 2) void gemm1_gelu(
    const bf16_t* __restrict__ Ahi, const bf16_t* __restrict__ Alo,
    const bf16_t* __restrict__ BThi, const bf16_t* __restrict__ BTlo,
    const float* __restrict__ bias,
    bf16_t* __restrict__ Chi, bf16_t* __restrict__ Clo,
    int N, int K)
{
    constexpr int MT = BM / 32;
    constexpr int NT = BN / 32;
    constexpr int OPS_A = BM / 16;
    constexpr int OPS_B = BN / 16;
    constexpr int NOPS = 2 * OPS_A + 2 * OPS_B;

    __shared__ __align__(16) bf16_t smem[(2 * BM + 2 * BN) * 32];
    bf16_t* const As0 = smem;
    bf16_t* const As1 = smem + BM * 32;
    bf16_t* const Bs0 = smem + 2 * BM * 32;
    bf16_t* const Bs1 = smem + 2 * BM * 32 + BN * 32;

    const int tid  = threadIdx.x;
    const int lane = tid & 63;
    const int wid  = tid >> 6;
    const int wm   = wid & 1;
    const int wn   = wid >> 1;
    const int bm   = blockIdx.y * BM;
    const int bn   = blockIdx.x * BN;

    const int srow = lane >> 2;
    const int scol = (lane & 3) * 8;

    f32x4 acc[MT][NT];
#pragma unroll
    for (int i = 0; i < MT; ++i)
#pragma unroll
        for (int j = 0; j < NT; ++j)
            acc[i][j] = (f32x4){0.f, 0.f, 0.f, 0.f};

    const bf16_t* const gA0 = Ahi  + (size_t)bm * K;
    const bf16_t* const gA1 = Alo  + (size_t)bm * K;
    const bf16_t* const gB0 = BThi + (size_t)bn * K;
    const bf16_t* const gB1 = BTlo + (size_t)bn * K;

    const int fr = lane & 15;
    const int fq = lane >> 4;

    for (int kt = 0; kt < K; kt += 32) {
        __syncthreads();
#pragma unroll
        for (int o = 0; o < NOPS; ++o) {
            if ((o & 3) != wid) continue;
            const bf16_t* gsrc;
            bf16_t* lbase;
            int q;
            if (o < OPS_A)                  { q = o;                     gsrc = gA0; lbase = As0; }
            else if (o < 2 * OPS_A)         { q = o - OPS_A;             gsrc = gA1; lbase = As1; }
            else if (o < 2 * OPS_A + OPS_B) { q = o - 2 * OPS_A;         gsrc = gB0; lbase = Bs0; }
            else                            { q = o - 2 * OPS_A - OPS_B; gsrc = gB1; lbase = Bs1; }
            async_cp16(gsrc + (size_t)(q * 16 + srow) * K + kt + scol,
                       lbase + q * 16 * 32);
        }
        __syncthreads();

        bf16x8 ah[MT], al[MT], bh[NT], bl[NT];
#pragma unroll
        for (int i = 0; i < MT; ++i) {
            const int row = wm * (BM / 2) + i * 16 + fr;
            ah[i] = *(const bf16x8*)(As0 + row * 32 + fq * 8);
            al[i] = *(const bf16x8*)(As1 + row * 32 + fq * 8);
        }
#pragma unroll
        for (int j = 0; j < NT; ++j) {
            const int row = wn * (BN / 2) + j * 16 + fr;
            bh[j] = *(const bf16x8*)(Bs0 + row * 32 + fq * 8);
            bl[j] = *(const bf16x8*)(Bs1 + row * 32 + fq * 8);
        }
#pragma unroll
        for (int i = 0; i < MT; ++i)
#pragma unroll
            for (int j = 0; j < NT; ++j) {
                acc[i][j] = __builtin_amdgcn_mfma_f32_16x16x32_bf16(ah[i], bh[j], acc[i][j], 0, 0, 0);
                acc[i][j] = __builtin_amdgcn_mfma_f32_16x16x32_bf16(ah[i], bl[j], acc[i][j], 0, 0, 0);
                acc[i][j] = __builtin_amdgcn_mfma_f32_16x16x32_bf16(al[i], bh[j], acc[i][j], 0, 0, 0);
            }
    }

    // C/D layout: col = lane&15, row = (lane>>4)*4 + reg
#pragma unroll
    for (int i = 0; i < MT; ++i)
#pragma unroll
        for (int j = 0; j < NT; ++j) {
            const int col  = bn + wn * (BN / 2) + j * 16 + fr;
            const int row0 = bm + wm * (BM / 2) + i * 16 + fq * 4;
            const float bj = bias[col];
#pragma unroll
            for (int r = 0; r < 4; ++r) {
                float v = gelu_exact(acc[i][j][r] + bj);
                bf16_t h = (bf16_t)v;
                bf16_t l = (bf16_t)(v - (float)h);
                const size_t off = (size_t)(row0 + r) * N + col;
                Chi[off] = h;
                Clo[off] = l;
            }
        }
}

// ---------------------------------------------------------------------------
// GEMM2 fused: logits = hid@W2 + b2, then gumbel-hard mask + per-row count.
// BM=64, BN=64, full-K in block. Counts accumulated via fr-lane butterfly
// + one global atomic per (row, wave). out_n/ws_n must be pre-zeroed.
// mask rule: hard = (l+g0) > (g1-l)   (softmax is monotone, tau>0)
// ---------------------------------------------------------------------------
template<bool WNP>
__global__ __launch_bounds__(256, 2) void gemm2_mask(
    const bf16_t* __restrict__ Ahi, const bf16_t* __restrict__ Alo,
    const bf16_t* __restrict__ BThi, const bf16_t* __restrict__ BTlo,
    const float* __restrict__ bias, const float* __restrict__ g,
    float* __restrict__ out_mask, float* __restrict__ out_n,
    int* __restrict__ ws_n, int K, int NV)
{
    constexpr int BM = 64, BN = 64;
    constexpr int MT = 2, NT = 2;
    constexpr int OPS_A = 4, OPS_B = 4;
    constexpr int NOPS = 16;

    __shared__ __align__(16) bf16_t smem[(2 * BM + 2 * BN) * 32];
    bf16_t* const As0 = smem;
    bf16_t* const As1 = smem + BM * 32;
    bf16_t* const Bs0 = smem + 2 * BM * 32;
    bf16_t* const Bs1 = smem + 2 * BM * 32 + BN * 32;

    const int tid  = threadIdx.x;
    const int lane = tid & 63;
    const int wid  = tid >> 6;
    const int wm   = wid & 1;
    const int wn   = wid >> 1;
    const int bm   = blockIdx.y * BM;
    const int bn   = blockIdx.x * BN;

    const int srow = lane >> 2;
    const int scol = (lane & 3) * 8;

    f32x4 acc[MT][NT];
#pragma unroll
    for (int i = 0; i < MT; ++i)
#pragma unroll
        for (int j = 0; j < NT; ++j)
            acc[i][j] = (f32x4){0.f, 0.f, 0.f, 0.f};

    const bf16_t* const gA0 = Ahi  + (size_t)bm * K;
    const bf16_t* const gA1 = Alo  + (size_t)bm * K;
    const bf16_t* const gB0 = BThi + (size_t)bn * K;
    const bf16_t* const gB1 = BTlo + (size_t)bn * K;

    const int fr = lane & 15;
    const int fq = lane >> 4;

    for (int kt = 0; kt < K; kt += 32) {
        __syncthreads();
#pragma unroll
        for (int o = 0; o < NOPS; ++o) {
            if ((o & 3) != wid) continue;
            const bf16_t* gsrc;
            bf16_t* lbase;
            int q;
            if (o < OPS_A)                  { q = o;                     gsrc = gA0; lbase = As0; }
            else if (o < 2 * OPS_A)         { q = o - OPS_A;             gsrc = gA1; lbase = As1; }
            else if (o < 2 * OPS_A + OPS_B) { q = o - 2 * OPS_A;         gsrc = gB0; lbase = Bs0; }
            else                            { q = o - 2 * OPS_A - OPS_B; gsrc = gB1; lbase = Bs1; }
            async_cp16(gsrc + (size_t)(q * 16 + srow) * K + kt + scol,
                       lbase + q * 16 * 32);
        }
        __syncthreads();

        bf16x8 ah[MT], al[MT], bh[NT], bl[NT];
#pragma unroll
        for (int i = 0; i < MT; ++i) {
            const int row = wm * 32 + i * 16 + fr;
            ah[i] = *(const bf16x8*)(As0 + row * 32 + fq * 8);
            al[i] = *(const bf16x8*)(As1 + row * 32 + fq * 8);
        }
#pragma unroll
        for (int j = 0; j < NT; ++j) {
            const int row = wn * 32 + j * 16 + fr;
            bh[j] = *(const bf16x8*)(Bs0 + row * 32 + fq * 8);
            bl[j] = *(const bf16x8*)(Bs1 + row * 32 + fq * 8);
        }
#pragma unroll
        for (int i = 0; i < MT; ++i)
#pragma unroll
            for (int j = 0; j < NT; ++j) {
                acc[i][j] = __builtin_amdgcn_mfma_f32_16x16x32_bf16(ah[i], bh[j], acc[i][j], 0, 0, 0);
                acc[i][j] = __builtin_amdgcn_mfma_f32_16x16x32_bf16(ah[i], bl[j], acc[i][j], 0, 0, 0);
                acc[i][j] = __builtin_amdgcn_mfma_f32_16x16x32_bf16(al[i], bh[j], acc[i][j], 0, 0, 0);
            }
    }

    // epilogue: logits -> gumbel-hard mask + row counts
#pragma unroll
    for (int i = 0; i < MT; ++i) {
#pragma unroll
        for (int r = 0; r < 4; ++r) {
            const int row = bm + wm * 32 + i * 16 + fq * 4 + r;
            float s = 0.f;
#pragma unroll
            for (int j = 0; j < NT; ++j) {
                const int col = bn + wn * 32 + j * 16 + fr;
                if (col < NV) {
                    const float v = acc[i][j][r] + bias[col];
                    const size_t idx = (size_t)row * NV + col;
                    const float g0 = g[2 * idx + 0];
                    const float g1 = g[2 * idx + 1];
                    const float m = ((v + g0) > (g1 - v)) ? 1.f : 0.f;
                    out_mask[idx] = m;
                    s += m;
                }
            }
            // reduce over the 16 fr-lanes (xor masks stay within fq group)
            s += __shfl_xor(s, 1, 64);
            s += __shfl_xor(s, 2, 64);
            s += __shfl_xor(s, 4, 64);
            s += __shfl_xor(s, 8, 64);
            if (fr == 0) {
                atomicAdd(&out_n[row], s);
                if (WNP) atomicAdd(&ws_n[row], (int)s);
            }
        }
    }
}

// ---------------------------------------------------------------------------
// prep_all: one kernel, block-range dispatch.
//   [0, 4096)        : split particle_h -> pA planes (float4-wide)
//   [4096, 6144)     : split hyperedge_h -> hA planes
//   [6144, 7168)     : W1_p transpose+split (32x32 LDS tiles)
//   [7168, 7296)     : W2_p transpose+split
//   [7296, 7552)     : W1_h transpose+split
//   [7552, 7584)     : W2_h transpose+split (pad to HE_PAD rows)
//   [7584, 7616)     : edge_index + ws_jj
//   [7616, 7664)     : zero out_np / ws_np / out_nh
// ---------------------------------------------------------------------------
struct PrepArgs {
    const float *ph, *hh, *W1p, *W2p, *W1h, *W2h;
    bf16_t *pA_hi, *pA_lo, *hA_hi, *hA_lo;
    bf16_t *W1pT_hi, *W1pT_lo, *W2pT_hi, *W2pT_lo;
    bf16_t *W1hT_hi, *W1hT_lo, *W2hT_hi, *W2hT_lo;
    float *out_ei; int *ws_jj;
    float *out_np, *out_nh; int *ws_np;
};

__device__ __forceinline__ void split4(const float* x, bf16_t* hi, bf16_t* lo, int i) {
    typedef bf16_t bf16x4 __attribute__((ext_vector_type(4)));
    float4 v = ((const float4*)x)[i];
    float vv[4] = {v.x, v.y, v.z, v.w};
    bf16x4 h, l;
#pragma unroll
    for (int r = 0; r < 4; ++r) {
        bf16_t hh = (bf16_t)vv[r];
        h[r] = hh;
        l[r] = (bf16_t)(vv[r] - (float)hh);
    }
    ((bf16x4*)hi)[i] = h;
    ((bf16x4*)lo)[i] = l;
}

__device__ __forceinline__ void tsplit(
    const float* W, bf16_t* Thi, bf16_t* Tlo, int K, int N,
    int t, int nx, float (*sh)[33], int tid)
{
    const int n0 = (t % nx) * 32, k0 = (t / nx) * 32;
    const int tx = tid & 31, ty = tid >> 5;
    for (int r = ty; r < 32; r += 8) {
        const int n = n0 + tx;
        sh[r][tx] = (n < N) ? W[(size_t)(k0 + r) * N + n] : 0.f;
    }
    __syncthreads();
    for (int r = ty; r < 32; r += 8) {
        const float x = sh[tx][r];     // = W[k0+tx][n0+r]
        bf16_t h = (bf16_t)x;
        bf16_t l = (bf16_t)(x - (float)h);
        const size_t off = (size_t)(n0 + r) * K + k0 + tx;
        Thi[off] = h;
        Tlo[off] = l;
    }
}

__device__ __forceinline__ int tri_off(int i) { return (i * (255 - i)) >> 1; }

__global__ __launch_bounds__(256) void prep_all(PrepArgs a)
{
    __shared__ float sh[32][33];
    const int bid = blockIdx.x;
    const int tid = threadIdx.x;

    if (bid < 4096) {
        split4(a.ph, a.pA_hi, a.pA_lo, bid * 256 + tid);
    } else if (bid < 6144) {
        split4(a.hh, a.hA_hi, a.hA_lo, (bid - 4096) * 256 + tid);
    } else if (bid < 7168) {
        tsplit(a.W1p, a.W1pT_hi, a.W1pT_lo, P_HID, P_HID, bid - 6144, 32, sh, tid);
    } else if (bid < 7296) {
        tsplit(a.W2p, a.W2pT_hi, a.W2pT_lo, P_HID, MAX_P, bid - 7168, 4, sh, tid);
    } else if (bid < 7552) {
        tsplit(a.W1h, a.W1hT_hi, a.W1hT_lo, H_HID, H_HID, bid - 7296, 16, sh, tid);
    } else if (bid < 7584) {
        tsplit(a.W2h, a.W2hT_hi, a.W2hT_lo, H_HID, MAX_HE, bid - 7552, 2, sh, tid);
    } else if (bid < 7616) {
        const int e = (bid - 7584) * 256 + tid;
        if (e < E_MAX) {
            int i = (int)((255.0 - sqrt(65025.0 - 8.0 * (double)e)) * 0.5);
            if (i < 0) i = 0;
            if (i > 126) i = 126;
            while (i > 0 && tri_off(i) > e) --i;
            while (i < 126 && tri_off(i + 1) <= e) ++i;
            const int j = i + 1 + (e - tri_off(i));
            a.out_ei[e] = (float)i;
            a.out_ei[E_MAX + e] = (float)j;
            a.ws_jj[e] = j;
        }
    } else {
        const int gi = (bid - 7616) * 256 + tid;
        if (gi < B_SZ) {
            a.out_np[gi] = 0.f;
            a.ws_np[gi] = 0;
        } else if (gi < 2 * B_SZ) {
            a.out_nh[gi - B_SZ] = 0.f;
        }
    }
}

// ---------------------------------------------------------------------------
// edge_valid[b,e] = jj[e] < n_particles[b], float4-wide
// ---------------------------------------------------------------------------
__global__ __launch_bounds__(256) void edge_valid_kernel(
    const int* __restrict__ ws_jj, const int* __restrict__ ws_n,
    float* __restrict__ out, int total4)
{
    int idx = blockIdx.x * 256 + threadIdx.x;
    if (idx >= total4) return;
    int b = idx / E_MAX4;
    int q = idx - b * E_MAX4;
    int4 j4 = ((const int4*)ws_jj)[q];
    int n = ws_n[b];
    float4 v;
    v.x = (j4.x < n) ? 1.f : 0.f;
    v.y = (j4.y < n) ? 1.f : 0.f;
    v.z = (j4.z < n) ? 1.f : 0.f;
    v.w = (j4.w < n) ? 1.f : 0.f;
    ((float4*)out)[idx] = v;
}

// ---------------------------------------------------------------------------
extern "C" void kernel_launch(void* const* d_in, const int* in_sizes, int n_in,
                              void* d_out, int out_size, void* d_ws, size_t ws_size,
                              hipStream_t stream)
{
    const float* particle_h  = (const float*)d_in[0];
    const float* hyperedge_h = (const float*)d_in[2];
    const float* g_p  = (const float*)d_in[3];
    const float* g_h  = (const float*)d_in[4];
    const float* W1_p = (const float*)d_in[5];
    const float* b1_p = (const float*)d_in[6];
    const float* W2_p = (const float*)d_in[7];
    const float* b2_p = (const float*)d_in[8];
    const float* W1_h = (const float*)d_in[9];
    const float* b1_h = (const float*)d_in[10];
    const float* W2_h = (const float*)d_in[11];
    const float* b2_h = (const float*)d_in[12];

    float* out = (float*)d_out;
    float* out_pmask = out;                                   // 4096*128
    float* out_np    = out_pmask + (size_t)B_SZ * MAX_P;      // 4096
    float* out_ei    = out_np + B_SZ;                         // 2*8128
    float* out_ev    = out_ei + 2 * E_MAX;                    // 4096*8128
    float* out_hmask = out_ev + (size_t)B_SZ * E_MAX;         // 4096*42
    float* out_nh    = out_hmask + (size_t)B_SZ * MAX_HE;     // 4096

    char* w = (char*)d_ws;
    bf16_t* pA_hi   = (bf16_t*)w;  w += (size_t)B_SZ * P_HID * 2;
    bf16_t* pA_lo   = (bf16_t*)w;  w += (size_t)B_SZ * P_HID * 2;
    bf16_t* hA_hi   = (bf16_t*)w;  w += (size_t)B_SZ * H_HID * 2;
    bf16_t* hA_lo   = (bf16_t*)w;  w += (size_t)B_SZ * H_HID * 2;
    bf16_t* hidp_hi = (bf16_t*)w;  w += (size_t)B_SZ * P_HID * 2;
    bf16_t* hidp_lo = (bf16_t*)w;  w += (size_t)B_SZ * P_HID * 2;
    bf16_t* hidh_hi = (bf16_t*)w;  w += (size_t)B_SZ * H_HID * 2;
    bf16_t* hidh_lo = (bf16_t*)w;  w += (size_t)B_SZ * H_HID * 2;
    bf16_t* W1pT_hi = (bf16_t*)w;  w += (size_t)P_HID * P_HID * 2;
    bf16_t* W1pT_lo = (bf16_t*)w;  w += (size_t)P_HID * P_HID * 2;
    bf16_t* W2pT_hi = (bf16_t*)w;  w += (size_t)MAX_P * P_HID * 2;
    bf16_t* W2pT_lo = (bf16_t*)w;  w += (size_t)MAX_P * P_HID * 2;
    bf16_t* W1hT_hi = (bf16_t*)w;  w += (size_t)H_HID * H_HID * 2;
    bf16_t* W1hT_lo = (bf16_t*)w;  w += (size_t)H_HID * H_HID * 2;
    bf16_t* W2hT_hi = (bf16_t*)w;  w += (size_t)HE_PAD * H_HID * 2;
    bf16_t* W2hT_lo = (bf16_t*)w;  w += (size_t)HE_PAD * H_HID * 2;
    int*    ws_np   = (int*)w;     w += B_SZ * 4;
    int*    ws_jj   = (int*)w;

    // ---- 1: fused prep ----
    PrepArgs pa;
    pa.ph = particle_h; pa.hh = hyperedge_h;
    pa.W1p = W1_p; pa.W2p = W2_p; pa.W1h = W1_h; pa.W2h = W2_h;
    pa.pA_hi = pA_hi; pa.pA_lo = pA_lo; pa.hA_hi = hA_hi; pa.hA_lo = hA_lo;
    pa.W1pT_hi = W1pT_hi; pa.W1pT_lo = W1pT_lo;
    pa.W2pT_hi = W2pT_hi; pa.W2pT_lo = W2pT_lo;
    pa.W1hT_hi = W1hT_hi; pa.W1hT_lo = W1hT_lo;
    pa.W2hT_hi = W2hT_hi; pa.W2hT_lo = W2hT_lo;
    pa.out_ei = out_ei; pa.ws_jj = ws_jj;
    pa.out_np = out_np; pa.out_nh = out_nh; pa.ws_np = ws_np;
    prep_all<<<7664, 256, 0, stream>>>(pa);

    // ---- 2-3: hidden GEMMs (gelu, split-plane output) ----
    gemm1_gelu<64, 128><<<dim3(P_HID / 128, B_SZ / 64), 256, 0, stream>>>(
        pA_hi, pA_lo, W1pT_hi, W1pT_lo, b1_p, hidp_hi, hidp_lo, P_HID, P_HID);
    gemm1_gelu<64, 128><<<dim3(H_HID / 128, B_SZ / 64), 256, 0, stream>>>(
        hA_hi, hA_lo, W1hT_hi, W1hT_lo, b1_h, hidh_hi, hidh_lo, H_HID, H_HID);

    // ---- 4-5: logit GEMMs fused with gumbel mask + counts ----
    gemm2_mask<true><<<dim3(MAX_P / 64, B_SZ / 64), 256, 0, stream>>>(
        hidp_hi, hidp_lo, W2pT_hi, W2pT_lo, b2_p, g_p,
        out_pmask, out_np, ws_np, P_HID, MAX_P);
    gemm2_mask<false><<<dim3(1, B_SZ / 64), 256, 0, stream>>>(
        hidh_hi, hidh_lo, W2hT_hi, W2hT_lo, b2_h, g_h,
        out_hmask, out_nh, nullptr, H_HID, MAX_HE);

    // ---- 6: edge_valid ----
    edge_valid_kernel<<<(B_SZ * E_MAX4 + 255) / 256, 256, 0, stream>>>(
        ws_jj, ws_np, out_ev, B_SZ * E_MAX4);
}